// Round 7
// baseline (219.368 us; speedup 1.0000x reference)
//
#include <hip/hip_runtime.h>
#include <math.h>

#define NB 32
#define NN 262144
#define NG 256
#define NC 64             // chunks per batch
#define CH (NN/NC)        // 4096 elements per chunk
#define SC (CH/4)         // 1024 elements per wave (4 waves/block)
#define CD 64             // chunks per batch, apply pass
#define ELD (NN/CD)       // 4096 elements per apply block

// ---- Pass 1 (fused count + chunk-local stable sort + contiguous flush) ----
// Chunk-LOCAL sorted layout: chunk c's window sorted[b*NN + c*CH .. +CH) holds
// its elements grouped by gid (runs at local offset lb(c,g)). Group g's global
// element-order sequence = concat over c of run(c,g) -> k_sum walks runs and
// the fp32 chain stays bit-exact. No cross-chunk offsets -> count and scatter
// fuse into ONE kernel; flush is perfectly contiguous float4 (no write amp,
// no gbuf). Stability: wave ranges + stripe order + ballot rank, as before.
__global__ __launch_bounds__(256) void k_fused(const int* __restrict__ vr,
                                               const float* __restrict__ pr,
                                               unsigned* __restrict__ gid32,
                                               float* __restrict__ sorted,
                                               unsigned* __restrict__ cnt_loff){
  __shared__ float vbuf[CH];            // 16 KB sorted values
  __shared__ unsigned graw[CH/4];       // 4 KB packed u8 gids, element order
  __shared__ unsigned wcnt[4][NG];      // 4 KB histogram -> running counters
  __shared__ unsigned wsum[4];          // cross-wave scan scratch
  const int t    = threadIdx.x;
  const int lane = t & 63;
  const int w    = t >> 6;
  const int b = blockIdx.x / NC;
  const int c = blockIdx.x % NC;
  const size_t base = (size_t)b*NN + (size_t)c*CH;

  wcnt[0][t] = 0u; wcnt[1][t] = 0u; wcnt[2][t] = 0u; wcnt[3][t] = 0u;
  __syncthreads();

  // phase A: load vr, histogram per wave, emit packed gids (global + LDS)
  {
    const int4* v4 = (const int4*)(vr + base);
#pragma unroll
    for (int i = 0; i < 4; i++){
      int idx = w*256 + i*64 + lane;      // wave-contiguous quarter, coalesced
      int4 v = v4[idx];
      atomicAdd(&wcnt[w][v.x], 1u);
      atomicAdd(&wcnt[w][v.y], 1u);
      atomicAdd(&wcnt[w][v.z], 1u);
      atomicAdd(&wcnt[w][v.w], 1u);
      unsigned pk = (unsigned)v.x | ((unsigned)v.y << 8)
                  | ((unsigned)v.z << 16) | ((unsigned)v.w << 24);
      gid32[(base >> 2) + idx] = pk;      // for k_apply
      graw[idx] = pk;                     // for phase C (no global re-read)
    }
  }
  __syncthreads();

  // phase B: chunk-local exclusive scan over groups; seed per-wave counters
  {
    unsigned c0 = wcnt[0][t], c1 = wcnt[1][t], c2 = wcnt[2][t], c3 = wcnt[3][t];
    unsigned tot = c0 + c1 + c2 + c3;
    unsigned v = tot;                     // wave-inclusive scan over lanes
#pragma unroll
    for (int d = 1; d < 64; d <<= 1){
      unsigned y = __shfl_up(v, d, 64);
      if (lane >= d) v += y;
    }
    if (lane == 63) wsum[w] = v;
    __syncthreads();
    unsigned pre = 0;
#pragma unroll
    for (int k = 0; k < 3; k++) if (k < w) pre += wsum[k];
    unsigned lb = pre + v - tot;          // local exclusive prefix over groups
    wcnt[0][t] = lb;
    wcnt[1][t] = lb + c0;
    wcnt[2][t] = lb + c0 + c1;
    wcnt[3][t] = lb + c0 + c1 + c2;
    cnt_loff[((size_t)b*NC + c)*NG + t] = tot | (lb << 16);  // both <=4096
  }
  __syncthreads();

  // phase C: stable ballot scatter into LDS (per wave, element order)
  {
    const unsigned long long below = (lane == 0) ? 0ull : ((1ull << lane) - 1ull);
    const float* psrc = pr + base + (size_t)w*SC;
    const int shft = (lane & 3) * 8;

    float pv[16]; unsigned pk[16];        // batch all loads upfront
#pragma unroll
    for (int s = 0; s < 16; s++){
      pv[s] = psrc[s*64 + lane];
      pk[s] = graw[w*256 + s*16 + (lane >> 2)];   // 4-lane broadcast word
    }
#pragma unroll
    for (int s = 0; s < 16; s++){
      int g = (int)((pk[s] >> shft) & 255u);
      unsigned long long mask = ~0ull;
#pragma unroll
      for (int bit = 0; bit < 8; bit++){
        int bv = (g >> bit) & 1;
        unsigned long long bal = __ballot(bv);
        mask &= bv ? bal : ~bal;
      }
      int rank = __popcll(mask & below);
      unsigned old = wcnt[w][g];          // all lanes read pre-update value
      if (rank == 0) wcnt[w][g] = old + (unsigned)__popcll(mask);
      vbuf[old + (unsigned)rank] = pv[s];
    }
  }
  __syncthreads();

  // phase D: contiguous float4 flush (chunk-local dst == slot index)
  {
    float4* dst4 = (float4*)(sorted + base);
    const float4* src4 = (const float4*)vbuf;
#pragma unroll
    for (int k = 0; k < 4; k++) dst4[k*256 + t] = src4[k*256 + t];
  }
}

// ---- Pass 2: one LANE per (batch,group); walk the 64 chunk-local runs in
//      chunk order -> exact element-order fp32 chain (bit-exact). Run table
//      staged in LDS; 8-wide load batching inside runs. ----
__global__ __launch_bounds__(32) void k_sum(const float* __restrict__ sorted,
                                            const unsigned* __restrict__ cnt_loff,
                                            float* __restrict__ gsum,
                                            float* __restrict__ gmn,
                                            float* __restrict__ gmx){
  __shared__ unsigned tab[NC][32];
  const int lane = threadIdx.x;                  // 0..31
  const int b = blockIdx.x >> 3;                 // 8 blocks per batch
  const int gbase = (blockIdx.x & 7) << 5;
  const int g = gbase + lane;                    // one group per lane

  for (int c = 0; c < NC; c++)
    tab[c][lane] = cnt_loff[((size_t)b*NC + c)*NG + gbase + lane];
  __syncthreads();

  float s = 0.0f, mn = INFINITY, mx = -INFINITY;
#define CONS1(V) { s = __fadd_rn(s, (V)); mn = fminf(mn, (V)); mx = fmaxf(mx, (V)); }
  const float* bb = sorted + (size_t)b*NN;
  for (int c = 0; c < NC; c++){
    unsigned cl  = tab[c][lane];
    unsigned len = cl & 0xFFFFu;
    const float* p = bb + c*CH + (cl >> 16);
    unsigned i = 0;
    for (; i + 8 <= len; i += 8){                // 8 independent loads, then chain
      float a0 = p[i  ], a1 = p[i+1], a2 = p[i+2], a3 = p[i+3];
      float a4 = p[i+4], a5 = p[i+5], a6 = p[i+6], a7 = p[i+7];
      CONS1(a0) CONS1(a1) CONS1(a2) CONS1(a3)
      CONS1(a4) CONS1(a5) CONS1(a6) CONS1(a7)
    }
    for (; i < len; i++){ float a = p[i]; CONS1(a); }
  }
#undef CONS1

  gsum[b*NG + g] = s;
  gmn [b*NG + g] = mn;
  gmx [b*NG + g] = mx;
}

// ---- Pass 3: per-batch group pipeline (blend, stable rank, f0/f1, no_scale) ----
// params layout: SoA, params[(b*4 + comp)*NG + g]
__global__ __launch_bounds__(256) void k_pipeline(const float* __restrict__ gsum,
                                                  const float* __restrict__ gmn,
                                                  const float* __restrict__ gmx,
                                                  const float* __restrict__ inp_means,
                                                  const float* __restrict__ Wv,
                                                  float* __restrict__ params){
  const int b = blockIdx.x;
  const int g = threadIdx.x;
  __shared__ float vm[NG];
  __shared__ float vs[NG];

  const float s   = gsum[b*NG + g];   // empty group: len==0 -> s==0 (matches where(vany,...))
  const float mnf = gmn [b*NG + g];
  const float mxf = gmx [b*NG + g];
  const float W0 = Wv[0], W1 = Wv[1];
  float mean = __fdiv_rn(__fadd_rn(__fmul_rn(inp_means[b*NG + g], W0),
                                   __fmul_rn(s, W1)),
                         __fadd_rn(W0, W1));
  vm[g] = mean;
  __syncthreads();

  // stable rank == position after stable argsort
  int r = 0;
  for (int j = 0; j < NG; j++){
    float x = vm[j];
    r += (x < mean) || (x == mean && j < g);
  }
  vs[r] = mean;
  __syncthreads();

  float c0 = (r == 0)    ? vs[0]                     : vs[r-1];
  float c1 = vs[r];
  float c2 = (r == NG-1) ? __fmul_rn(vs[NG-1], 2.0f) : vs[r+1];
  float f0 = __fdiv_rn(__fadd_rn(c0, c1), 1.999f);
  float f1 = __fdiv_rn(__fadd_rn(c1, c2), 2.001f);

  bool ns = (mnf == mxf);
  params[(b*4 + 0)*NG + g] = ns ? 0.0f : mnf;                  // vmin_use
  params[(b*4 + 1)*NG + g] = ns ? 1.0f : __fsub_rn(mxf, mnf);  // range_use
  params[(b*4 + 2)*NG + g] = ns ? 1.0f : __fsub_rn(f1, f0);    // (f1-f0)_use
  params[(b*4 + 3)*NG + g] = ns ? 0.0f : f0;                   // f0_use
}

// ---- Pass 4: per-element apply, fp32 replicating reference op order ----
static __device__ __forceinline__ float apply_one(float p, unsigned g,
                                                  const float* __restrict__ sp0,
                                                  const float* __restrict__ sp1,
                                                  const float* __restrict__ sp2,
                                                  const float* __restrict__ sp3){
  float t1  = __fsub_rn(p, sp0[g]);
  float t3  = __fdiv_rn(t1, sp1[g]);
  float t5  = __fmul_rn(t3, sp2[g]);
  float tmp = __fadd_rn(t5, sp3[g]);
  bool bad = __builtin_isnan(tmp) || (tmp == 0.0f);
  float s = __fdiv_rn(p, bad ? 1.0f : tmp);
  bool bad2 = bad || __builtin_isnan(s) || __builtin_isinf(s);
  float sc = bad2 ? 0.0f : s;
  return __fmul_rn(p, sc);
}

__global__ __launch_bounds__(256) void k_apply(const float* __restrict__ pr,
                                               const unsigned* __restrict__ gid32,
                                               const float* __restrict__ params,
                                               float* __restrict__ out){
  __shared__ float sp0[NG], sp1[NG], sp2[NG], sp3[NG];
  const int t = threadIdx.x;
  const int b = blockIdx.x / CD;
  const int c = blockIdx.x % CD;

  sp0[t] = params[(b*4 + 0)*NG + t];
  sp1[t] = params[(b*4 + 1)*NG + t];
  sp2[t] = params[(b*4 + 2)*NG + t];
  sp3[t] = params[(b*4 + 3)*NG + t];
  __syncthreads();

  const size_t base = (size_t)b*NN + (size_t)c*ELD;
  const float4* p4 = (const float4*)(pr + base);
  float4* o4 = (float4*)(out + base);

#pragma unroll
  for (int i = 0; i < ELD/1024; i++){
    float4 p = p4[i*256 + t];
    unsigned pk = gid32[(base >> 2) + i*256 + t];
    float4 r;
    r.x = apply_one(p.x,  pk        & 255u, sp0, sp1, sp2, sp3);
    r.y = apply_one(p.y, (pk >>  8) & 255u, sp0, sp1, sp2, sp3);
    r.z = apply_one(p.z, (pk >> 16) & 255u, sp0, sp1, sp2, sp3);
    r.w = apply_one(p.w,  pk >> 24,         sp0, sp1, sp2, sp3);
    o4[i*256 + t] = r;
  }
}

extern "C" void kernel_launch(void* const* d_in, const int* in_sizes, int n_in,
                              void* d_out, int out_size, void* d_ws, size_t ws_size,
                              hipStream_t stream){
  const float* pr        = (const float*)d_in[0];
  const float* inp_means = (const float*)d_in[1];
  const int*   vr        = (const int*)d_in[2];
  const float* W         = (const float*)d_in[3];
  float* out = (float*)d_out;

  char* ws = (char*)d_ws;
  size_t o = 0;
  unsigned* gid32    = (unsigned*)(ws + o); o += (size_t)NB*NN;        // 8 MB packed u8 gids
  unsigned* cnt_loff = (unsigned*)(ws + o); o += (size_t)NB*NC*NG*4;   // 2 MB {len | loff<<16}
  float*    gsum     = (float*)   (ws + o); o += (size_t)NB*NG*4;
  float*    gmn      = (float*)   (ws + o); o += (size_t)NB*NG*4;
  float*    gmx      = (float*)   (ws + o); o += (size_t)NB*NG*4;
  float*    params   = (float*)   (ws + o); o += (size_t)NB*NG*16;     // 128 KB (SoA)
  // chunk-locally-sorted values live in d_out (fully overwritten by k_apply)
  float* sorted = out;

  k_fused   <<<NB*NC, 256, 0, stream>>>(vr, pr, gid32, sorted, cnt_loff);
  k_sum     <<<NB*8,   32, 0, stream>>>(sorted, cnt_loff, gsum, gmn, gmx);
  k_pipeline<<<NB,    256, 0, stream>>>(gsum, gmn, gmx, inp_means, W, params);
  k_apply   <<<NB*CD, 256, 0, stream>>>(pr, gid32, params, out);
}

// Round 8
// 180.695 us; speedup vs baseline: 1.2140x; 1.2140x over previous
//
#include <hip/hip_runtime.h>
#include <math.h>

#define NB 32
#define NN 262144
#define NG 256
#define NC 64             // chunks per batch
#define CH (NN/NC)        // 4096 elements per chunk
#define SC (CH/4)         // 1024 elements per wave (4 waves/block)
#define CD 64             // chunks per batch, apply pass
#define ELD (NN/CD)       // 4096 elements per apply block

// ============================ FUSED PIPELINE ============================

// ---- Pass 1 (fused count + chunk-local stable sort + contiguous flush) ----
// Chunk c's window sorted[b*NN + c*CH .. +CH) holds its elements grouped by
// gid (runs at local offset lb(c,g)). Stability: wave ranges + stripe order +
// ballot rank -> global element order preserved within runs; k_gather then
// concatenates runs chunk-major == element order (fp32 chain bit-exact).
__global__ __launch_bounds__(256) void k_fused(const int* __restrict__ vr,
                                               const float* __restrict__ pr,
                                               unsigned* __restrict__ gid32,
                                               float* __restrict__ sortedL,
                                               unsigned* __restrict__ cnt_loff){
  __shared__ float vbuf[CH];            // 16 KB sorted values
  __shared__ unsigned graw[CH/4];       // 4 KB packed u8 gids, element order
  __shared__ unsigned wcnt[4][NG];      // 4 KB histogram -> running counters
  __shared__ unsigned wsum[4];          // cross-wave scan scratch
  const int t    = threadIdx.x;
  const int lane = t & 63;
  const int w    = t >> 6;
  const int b = blockIdx.x / NC;
  const int c = blockIdx.x % NC;
  const size_t base = (size_t)b*NN + (size_t)c*CH;

  wcnt[0][t] = 0u; wcnt[1][t] = 0u; wcnt[2][t] = 0u; wcnt[3][t] = 0u;
  __syncthreads();

  // phase A: load vr, histogram per wave, emit packed gids (global + LDS)
  {
    const int4* v4 = (const int4*)(vr + base);
#pragma unroll
    for (int i = 0; i < 4; i++){
      int idx = w*256 + i*64 + lane;      // wave-contiguous quarter, coalesced
      int4 v = v4[idx];
      atomicAdd(&wcnt[w][v.x], 1u);
      atomicAdd(&wcnt[w][v.y], 1u);
      atomicAdd(&wcnt[w][v.z], 1u);
      atomicAdd(&wcnt[w][v.w], 1u);
      unsigned pk = (unsigned)v.x | ((unsigned)v.y << 8)
                  | ((unsigned)v.z << 16) | ((unsigned)v.w << 24);
      gid32[(base >> 2) + idx] = pk;      // for k_apply
      graw[idx] = pk;                     // for phase C (no global re-read)
    }
  }
  __syncthreads();

  // phase B: chunk-local exclusive scan over groups; seed per-wave counters
  {
    unsigned c0 = wcnt[0][t], c1 = wcnt[1][t], c2 = wcnt[2][t], c3 = wcnt[3][t];
    unsigned tot = c0 + c1 + c2 + c3;
    unsigned v = tot;                     // wave-inclusive scan over lanes
#pragma unroll
    for (int d = 1; d < 64; d <<= 1){
      unsigned y = __shfl_up(v, d, 64);
      if (lane >= d) v += y;
    }
    if (lane == 63) wsum[w] = v;
    __syncthreads();
    unsigned pre = 0;
#pragma unroll
    for (int k = 0; k < 3; k++) if (k < w) pre += wsum[k];
    unsigned lb = pre + v - tot;          // local exclusive prefix over groups
    wcnt[0][t] = lb;
    wcnt[1][t] = lb + c0;
    wcnt[2][t] = lb + c0 + c1;
    wcnt[3][t] = lb + c0 + c1 + c2;
    cnt_loff[((size_t)b*NC + c)*NG + t] = tot | (lb << 16);  // both <=4096
  }
  __syncthreads();

  // phase C: stable ballot scatter into LDS (per wave, element order)
  {
    const unsigned long long below = (lane == 0) ? 0ull : ((1ull << lane) - 1ull);
    const float* psrc = pr + base + (size_t)w*SC;
    const int shft = (lane & 3) * 8;

    float pv[16]; unsigned pk[16];        // batch all loads upfront
#pragma unroll
    for (int s = 0; s < 16; s++){
      pv[s] = psrc[s*64 + lane];
      pk[s] = graw[w*256 + s*16 + (lane >> 2)];   // 4-lane broadcast word
    }
#pragma unroll
    for (int s = 0; s < 16; s++){
      int g = (int)((pk[s] >> shft) & 255u);
      unsigned long long mask = ~0ull;
#pragma unroll
      for (int bit = 0; bit < 8; bit++){
        int bv = (g >> bit) & 1;
        unsigned long long bal = __ballot(bv);
        mask &= bv ? bal : ~bal;
      }
      int rank = __popcll(mask & below);
      unsigned old = wcnt[w][g];          // all lanes read pre-update value
      if (rank == 0) wcnt[w][g] = old + (unsigned)__popcll(mask);
      vbuf[old + (unsigned)rank] = pv[s];
    }
  }
  __syncthreads();

  // phase D: contiguous float4 flush (chunk-local dst == slot index)
  {
    float4* dst4 = (float4*)(sortedL + base);
    const float4* src4 = (const float4*)vbuf;
#pragma unroll
    for (int k = 0; k < 4; k++) dst4[k*256 + t] = src4[k*256 + t];
  }
}

// ---- Pass 2: gather chunk-local -> globally sorted (pure permutation copy).
// map (slot->gid) rebuilt in LDS from this block's own cnt_loff row (byte
// writes, race-free: runs partition [0,CH)). bias via L2-hot column walk +
// shfl scan (R6-proven). Output array bit-identical to R6's sorted. ----
__global__ __launch_bounds__(256) void k_gather(const float* __restrict__ sortedL,
                                                const unsigned* __restrict__ cnt_loff,
                                                float* __restrict__ sortedG,
                                                unsigned* __restrict__ grpbase,
                                                unsigned* __restrict__ grplen){
  __shared__ unsigned char map8[CH];    // 4 KB slot -> gid
  __shared__ unsigned bias[NG];         // 1 KB global_dest - local_base
  __shared__ unsigned wsum[4];
  const int t    = threadIdx.x;
  const int lane = t & 63;
  const int w    = t >> 6;
  const int b = blockIdx.x / NC;
  const int c = blockIdx.x % NC;

  const unsigned* col = cnt_loff + (size_t)b*NC*NG + t;   // thread t == group
  unsigned own = col[(size_t)c*NG];
  unsigned len = own & 0xFFFFu, lb = own >> 16;
  for (unsigned i = 0; i < len; i++) map8[lb + i] = (unsigned char)t;

  unsigned tot_all = 0, tot_before = 0;
#pragma unroll 8
  for (int cc = 0; cc < NC; cc++){
    unsigned x = col[(size_t)cc*NG];
    unsigned tt = x & 0xFFFFu;
    tot_all += tt;
    if (cc < c) tot_before += tt;       // uniform branch per block
  }
  unsigned v = tot_all;                 // wave-inclusive scan over lanes
#pragma unroll
  for (int d = 1; d < 64; d <<= 1){
    unsigned y = __shfl_up(v, d, 64);
    if (lane >= d) v += y;
  }
  if (lane == 63) wsum[w] = v;
  __syncthreads();
  unsigned pre = 0;
#pragma unroll
  for (int k = 0; k < 3; k++) if (k < w) pre += wsum[k];
  unsigned base_g = pre + v - tot_all;  // exclusive prefix over groups
  bias[t] = (base_g + tot_before) - lb;
  if (c == 0){                          // publish for k_sum
    grpbase[b*NG + t] = base_g;
    grplen [b*NG + t] = tot_all;
  }
  __syncthreads();

  const float4* src4 = (const float4*)(sortedL + (size_t)b*NN + (size_t)c*CH);
  float* dst = sortedG + (size_t)b*NN;
  const unsigned* m32 = (const unsigned*)map8;
#pragma unroll
  for (int k = 0; k < 4; k++){
    int q = k*256 + t;                  // quad index
    unsigned mq = m32[q];
    float4 vv = src4[q];                // coalesced 16B read
    int p = q << 2;
    dst[bias[ mq        & 255u] + (unsigned)p    ] = vv.x;
    dst[bias[(mq >>  8) & 255u] + (unsigned)p + 1] = vv.y;
    dst[bias[(mq >> 16) & 255u] + (unsigned)p + 2] = vv.z;
    dst[bias[ mq >> 24        ] + (unsigned)p + 3] = vv.w;
  }
}

// ============================ FALLBACK (R6) ============================

__global__ __launch_bounds__(256) void k_count(const int* __restrict__ vr,
                                               unsigned long long* __restrict__ wcnt16,
                                               unsigned* __restrict__ gid32){
  __shared__ unsigned sc[4][NG];
  const int t    = threadIdx.x;
  const int lane = t & 63;
  const int w    = t >> 6;
  sc[0][t] = 0u; sc[1][t] = 0u; sc[2][t] = 0u; sc[3][t] = 0u;
  __syncthreads();

  const int b = blockIdx.x / NC;
  const int c = blockIdx.x % NC;
  const size_t base = (size_t)b*NN + (size_t)c*CH;
  const int4* v4 = (const int4*)(vr + base);

#pragma unroll
  for (int i = 0; i < 4; i++){
    int idx = w*256 + i*64 + lane;
    int4 v = v4[idx];
    atomicAdd(&sc[w][v.x], 1u);
    atomicAdd(&sc[w][v.y], 1u);
    atomicAdd(&sc[w][v.z], 1u);
    atomicAdd(&sc[w][v.w], 1u);
    gid32[(base >> 2) + idx] =
      (unsigned)v.x | ((unsigned)v.y << 8) | ((unsigned)v.z << 16) | ((unsigned)v.w << 24);
  }
  __syncthreads();

  unsigned c0 = sc[0][t], c1 = sc[1][t], c2 = sc[2][t], c3 = sc[3][t];
  const size_t cb = (size_t)b*NC + c;
  wcnt16[cb*NG + t] = (unsigned long long)c0
                    | ((unsigned long long)c1 << 16)
                    | ((unsigned long long)c2 << 32)
                    | ((unsigned long long)c3 << 48);
}

__global__ __launch_bounds__(256) void k_scatter(const float* __restrict__ pr,
                                                 const unsigned* __restrict__ gid32,
                                                 const unsigned long long* __restrict__ wcnt16,
                                                 float* __restrict__ sorted,
                                                 unsigned* __restrict__ grpbase,
                                                 unsigned* __restrict__ grplen){
  __shared__ float vbuf[CH];
  __shared__ unsigned char gbuf[CH];
  __shared__ unsigned wcnt[4][NG];
  __shared__ unsigned bias[NG];
  __shared__ unsigned wsumA[4];
  __shared__ unsigned wsumO[4];
  const int t    = threadIdx.x;
  const int lane = t & 63;
  const int w    = t >> 6;
  const int b = blockIdx.x / NC;
  const int c = blockIdx.x % NC;
  const size_t base = (size_t)b*NN + (size_t)c*CH;

  {
    const unsigned long long* tab = wcnt16 + (size_t)b*NC*NG + t;
    unsigned long long own = 0;
    unsigned tot_all = 0, tot_before = 0;
#pragma unroll 8
    for (int cc = 0; cc < NC; cc++){
      unsigned long long x = tab[(size_t)cc*NG];
      unsigned lo = (unsigned)x, hi = (unsigned)(x >> 32);
      unsigned tt = (lo & 0xFFFFu) + (lo >> 16) + (hi & 0xFFFFu) + (hi >> 16);
      tot_all += tt;
      if (cc < c)  tot_before += tt;
      if (cc == c) own = x;
    }
    unsigned lo = (unsigned)own, hi = (unsigned)(own >> 32);
    unsigned w0 = lo & 0xFFFFu, w1 = lo >> 16, w2 = hi & 0xFFFFu, w3 = hi >> 16;
    unsigned tot_own = w0 + w1 + w2 + w3;

    unsigned va = tot_all, vo = tot_own;
#pragma unroll
    for (int d = 1; d < 64; d <<= 1){
      unsigned ya = __shfl_up(va, d, 64);
      unsigned yo = __shfl_up(vo, d, 64);
      if (lane >= d){ va += ya; vo += yo; }
    }
    if (lane == 63){ wsumA[w] = va; wsumO[w] = vo; }
    __syncthreads();
    unsigned preA = 0, preO = 0;
#pragma unroll
    for (int k = 0; k < 3; k++) if (k < w){ preA += wsumA[k]; preO += wsumO[k]; }
    unsigned base_g = preA + va - tot_all;
    unsigned lb     = preO + vo - tot_own;
    wcnt[0][t] = lb;
    wcnt[1][t] = lb + w0;
    wcnt[2][t] = lb + w0 + w1;
    wcnt[3][t] = lb + w0 + w1 + w2;
    bias[t] = (base_g + tot_before) - lb;
    if (c == 0){
      grpbase[b*NG + t] = base_g;
      grplen [b*NG + t] = tot_all;
    }
  }
  __syncthreads();

  {
    const unsigned long long below = (lane == 0) ? 0ull : ((1ull << lane) - 1ull);
    const float*    psrc = pr    + base        + (size_t)w*SC;
    const unsigned* gsrc = gid32 + (base >> 2) + (size_t)w*(SC/4);
    const int shft = (lane & 3) * 8;

    float pv[16]; unsigned pk[16];
#pragma unroll
    for (int s = 0; s < 16; s++){
      pv[s] = psrc[s*64 + lane];
      pk[s] = gsrc[s*16 + (lane >> 2)];
    }
#pragma unroll
    for (int s = 0; s < 16; s++){
      int g = (int)((pk[s] >> shft) & 255u);
      unsigned long long mask = ~0ull;
#pragma unroll
      for (int bit = 0; bit < 8; bit++){
        int bv = (g >> bit) & 1;
        unsigned long long bal = __ballot(bv);
        mask &= bv ? bal : ~bal;
      }
      int rank = __popcll(mask & below);
      unsigned old = wcnt[w][g];
      if (rank == 0) wcnt[w][g] = old + (unsigned)__popcll(mask);
      vbuf[old + (unsigned)rank] = pv[s];
      gbuf[old + (unsigned)rank] = (unsigned char)g;
    }
  }
  __syncthreads();

  {
    float* dst = sorted + (size_t)b*NN;
    const unsigned* gbuf32 = (const unsigned*)gbuf;
#pragma unroll
    for (int k = 0; k < CH/256; k++){
      int p = k*256 + t;
      unsigned packed = gbuf32[p >> 2];
      unsigned g = (packed >> ((p & 3) * 8)) & 255u;
      dst[bias[g] + (unsigned)p] = vbuf[p];
    }
  }
}

// ============================ SHARED TAIL ============================

// ---- one LANE per (batch,group); float4 loads, 8-deep register pipeline.
//      Scalar head to 16B alignment + scalar tail keep the fp32 add chain in
//      exact element order (bit-exact). ----
__global__ __launch_bounds__(32) void k_sum(const float* __restrict__ sorted,
                                            const unsigned* __restrict__ grpbase,
                                            const unsigned* __restrict__ grplen,
                                            float* __restrict__ gsum,
                                            float* __restrict__ gmn,
                                            float* __restrict__ gmx){
  const int lane = threadIdx.x;                  // 0..31
  const int b = blockIdx.x >> 3;                 // 8 blocks per batch
  const int g = ((blockIdx.x & 7) << 5) + lane;  // one group per lane

  const unsigned base = grpbase[b*NG + g];
  const unsigned len  = grplen [b*NG + g];
  const float* sp = sorted + (size_t)b*NN + base;

  float s = 0.0f, mn = INFINITY, mx = -INFINITY;

  unsigned head = (4u - ((unsigned)(((size_t)sp) >> 2) & 3u)) & 3u;
  if (head > len) head = len;
  for (unsigned i = 0; i < head; i++){
    float v = sp[i];
    s = __fadd_rn(s, v); mn = fminf(mn, v); mx = fmaxf(mx, v);
  }
  const float4* f4 = (const float4*)(sp + head);
  const unsigned rem   = len - head;
  const unsigned nfull = rem >> 4;               // 16-elem batches (4 x float4)

  float4 b0[4], b1[4], b2[4], b3[4], b4[4], b5[4], b6[4], b7[4];
#define LOADV(D, K) { D[0]=f4[(K)*4+0]; D[1]=f4[(K)*4+1]; D[2]=f4[(K)*4+2]; D[3]=f4[(K)*4+3]; }
#define CONS1(V)    { s=__fadd_rn(s,(V)); mn=fminf(mn,(V)); mx=fmaxf(mx,(V)); }
#define CONSV(D)    { _Pragma("unroll") for (int j = 0; j < 4; j++){ float4 q = D[j]; \
                      CONS1(q.x) CONS1(q.y) CONS1(q.z) CONS1(q.w) } }

  if (nfull > 0) LOADV(b0, 0)
  if (nfull > 1) LOADV(b1, 1)
  if (nfull > 2) LOADV(b2, 2)
  if (nfull > 3) LOADV(b3, 3)
  if (nfull > 4) LOADV(b4, 4)
  if (nfull > 5) LOADV(b5, 5)
  if (nfull > 6) LOADV(b6, 6)
  if (nfull > 7) LOADV(b7, 7)
  unsigned k = 0;
  for (; k + 8 <= nfull; k += 8){
    CONSV(b0) if (k +  8 < nfull) LOADV(b0, k +  8)
    CONSV(b1) if (k +  9 < nfull) LOADV(b1, k +  9)
    CONSV(b2) if (k + 10 < nfull) LOADV(b2, k + 10)
    CONSV(b3) if (k + 11 < nfull) LOADV(b3, k + 11)
    CONSV(b4) if (k + 12 < nfull) LOADV(b4, k + 12)
    CONSV(b5) if (k + 13 < nfull) LOADV(b5, k + 13)
    CONSV(b6) if (k + 14 < nfull) LOADV(b6, k + 14)
    CONSV(b7) if (k + 15 < nfull) LOADV(b7, k + 15)
  }
  {
    unsigned r = nfull - k;
    if (r > 0) CONSV(b0)
    if (r > 1) CONSV(b1)
    if (r > 2) CONSV(b2)
    if (r > 3) CONSV(b3)
    if (r > 4) CONSV(b4)
    if (r > 5) CONSV(b5)
    if (r > 6) CONSV(b6)
  }
  for (unsigned i = head + (nfull << 4); i < len; i++){
    float v = sp[i];
    s = __fadd_rn(s, v); mn = fminf(mn, v); mx = fmaxf(mx, v);
  }
#undef LOADV
#undef CONS1
#undef CONSV

  gsum[b*NG + g] = s;
  gmn [b*NG + g] = mn;
  gmx [b*NG + g] = mx;
}

// ---- per-batch group pipeline (blend, stable rank, f0/f1, no_scale) ----
__global__ __launch_bounds__(256) void k_pipeline(const float* __restrict__ gsum,
                                                  const float* __restrict__ gmn,
                                                  const float* __restrict__ gmx,
                                                  const float* __restrict__ inp_means,
                                                  const float* __restrict__ Wv,
                                                  float* __restrict__ params){
  const int b = blockIdx.x;
  const int g = threadIdx.x;
  __shared__ float vm[NG];
  __shared__ float vs[NG];

  const float s   = gsum[b*NG + g];
  const float mnf = gmn [b*NG + g];
  const float mxf = gmx [b*NG + g];
  const float W0 = Wv[0], W1 = Wv[1];
  float mean = __fdiv_rn(__fadd_rn(__fmul_rn(inp_means[b*NG + g], W0),
                                   __fmul_rn(s, W1)),
                         __fadd_rn(W0, W1));
  vm[g] = mean;
  __syncthreads();

  int r = 0;
  for (int j = 0; j < NG; j++){
    float x = vm[j];
    r += (x < mean) || (x == mean && j < g);
  }
  vs[r] = mean;
  __syncthreads();

  float c0 = (r == 0)    ? vs[0]                     : vs[r-1];
  float c1 = vs[r];
  float c2 = (r == NG-1) ? __fmul_rn(vs[NG-1], 2.0f) : vs[r+1];
  float f0 = __fdiv_rn(__fadd_rn(c0, c1), 1.999f);
  float f1 = __fdiv_rn(__fadd_rn(c1, c2), 2.001f);

  bool ns = (mnf == mxf);
  params[(b*4 + 0)*NG + g] = ns ? 0.0f : mnf;
  params[(b*4 + 1)*NG + g] = ns ? 1.0f : __fsub_rn(mxf, mnf);
  params[(b*4 + 2)*NG + g] = ns ? 1.0f : __fsub_rn(f1, f0);
  params[(b*4 + 3)*NG + g] = ns ? 0.0f : f0;
}

// ---- per-element apply, fp32 replicating reference op order ----
static __device__ __forceinline__ float apply_one(float p, unsigned g,
                                                  const float* __restrict__ sp0,
                                                  const float* __restrict__ sp1,
                                                  const float* __restrict__ sp2,
                                                  const float* __restrict__ sp3){
  float t1  = __fsub_rn(p, sp0[g]);
  float t3  = __fdiv_rn(t1, sp1[g]);
  float t5  = __fmul_rn(t3, sp2[g]);
  float tmp = __fadd_rn(t5, sp3[g]);
  bool bad = __builtin_isnan(tmp) || (tmp == 0.0f);
  float s = __fdiv_rn(p, bad ? 1.0f : tmp);
  bool bad2 = bad || __builtin_isnan(s) || __builtin_isinf(s);
  float sc = bad2 ? 0.0f : s;
  return __fmul_rn(p, sc);
}

__global__ __launch_bounds__(256) void k_apply(const float* __restrict__ pr,
                                               const unsigned* __restrict__ gid32,
                                               const float* __restrict__ params,
                                               float* __restrict__ out){
  __shared__ float sp0[NG], sp1[NG], sp2[NG], sp3[NG];
  const int t = threadIdx.x;
  const int b = blockIdx.x / CD;
  const int c = blockIdx.x % CD;

  sp0[t] = params[(b*4 + 0)*NG + t];
  sp1[t] = params[(b*4 + 1)*NG + t];
  sp2[t] = params[(b*4 + 2)*NG + t];
  sp3[t] = params[(b*4 + 3)*NG + t];
  __syncthreads();

  const size_t base = (size_t)b*NN + (size_t)c*ELD;
  const float4* p4 = (const float4*)(pr + base);
  float4* o4 = (float4*)(out + base);

#pragma unroll
  for (int i = 0; i < ELD/1024; i++){
    float4 p = p4[i*256 + t];
    unsigned pk = gid32[(base >> 2) + i*256 + t];
    float4 r;
    r.x = apply_one(p.x,  pk        & 255u, sp0, sp1, sp2, sp3);
    r.y = apply_one(p.y, (pk >>  8) & 255u, sp0, sp1, sp2, sp3);
    r.z = apply_one(p.z, (pk >> 16) & 255u, sp0, sp1, sp2, sp3);
    r.w = apply_one(p.w,  pk >> 24,         sp0, sp1, sp2, sp3);
    o4[i*256 + t] = r;
  }
}

extern "C" void kernel_launch(void* const* d_in, const int* in_sizes, int n_in,
                              void* d_out, int out_size, void* d_ws, size_t ws_size,
                              hipStream_t stream){
  const float* pr        = (const float*)d_in[0];
  const float* inp_means = (const float*)d_in[1];
  const int*   vr        = (const int*)d_in[2];
  const float* W         = (const float*)d_in[3];
  float* out = (float*)d_out;

  char* ws = (char*)d_ws;
  size_t o = 0;
  unsigned* gid32   = (unsigned*)(ws + o); o += (size_t)NB*NN;       // 8 MB
  unsigned* grpbase = (unsigned*)(ws + o); o += (size_t)NB*NG*4;
  unsigned* grplen  = (unsigned*)(ws + o); o += (size_t)NB*NG*4;
  float*    gsum    = (float*)   (ws + o); o += (size_t)NB*NG*4;
  float*    gmn     = (float*)   (ws + o); o += (size_t)NB*NG*4;
  float*    gmx     = (float*)   (ws + o); o += (size_t)NB*NG*4;
  float*    params  = (float*)   (ws + o); o += (size_t)NB*NG*16;    // 128 KB

  // fused-path extras: cnt_loff (2 MB) + global-sorted (32 MB)
  size_t need_fused = o + (size_t)NB*NC*NG*4 + (size_t)NB*NN*4;

  if (ws_size >= need_fused){
    unsigned* cnt_loff = (unsigned*)(ws + o); o += (size_t)NB*NC*NG*4;
    float*    sortedG  = (float*)   (ws + o); o += (size_t)NB*NN*4;
    float* sortedL = out;   // chunk-local sorted; overwritten by k_apply later

    k_fused   <<<NB*NC, 256, 0, stream>>>(vr, pr, gid32, sortedL, cnt_loff);
    k_gather  <<<NB*NC, 256, 0, stream>>>(sortedL, cnt_loff, sortedG, grpbase, grplen);
    k_sum     <<<NB*8,   32, 0, stream>>>(sortedG, grpbase, grplen, gsum, gmn, gmx);
    k_pipeline<<<NB,    256, 0, stream>>>(gsum, gmn, gmx, inp_means, W, params);
    k_apply   <<<NB*CD, 256, 0, stream>>>(pr, gid32, params, out);
  } else {
    // R6 fallback (needs only +4 MB)
    unsigned long long* wcnt16 = (unsigned long long*)(ws + o); o += (size_t)NB*NC*NG*8;
    float* sorted = out;

    k_count   <<<NB*NC, 256, 0, stream>>>(vr, wcnt16, gid32);
    k_scatter <<<NB*NC, 256, 0, stream>>>(pr, gid32, wcnt16, sorted, grpbase, grplen);
    k_sum     <<<NB*8,   32, 0, stream>>>(sorted, grpbase, grplen, gsum, gmn, gmx);
    k_pipeline<<<NB,    256, 0, stream>>>(gsum, gmn, gmx, inp_means, W, params);
    k_apply   <<<NB*CD, 256, 0, stream>>>(pr, gid32, params, out);
  }
}

// Round 9
// 169.017 us; speedup vs baseline: 1.2979x; 1.0691x over previous
//
#include <hip/hip_runtime.h>
#include <math.h>

#define NB 32
#define NN 262144
#define NG 256
#define NC 64             // chunks per batch
#define CH (NN/NC)        // 4096 elements per chunk
#define SC (CH/4)         // 1024 elements per wave (4 waves/block)
#define CD 64             // chunks per batch, apply pass
#define ELD (NN/CD)       // 4096 elements per apply block

// ---- Pass 1: per-(batch,chunk,WAVE,group) counts (packed u16x4) + packed u8
//      gid emission. Wave w counts exactly elements [w*1024,(w+1)*1024) so the
//      counts seed k_scatter's running counters directly (no re-histogram). ----
__global__ __launch_bounds__(256) void k_count(const int* __restrict__ vr,
                                               unsigned long long* __restrict__ wcnt16,
                                               unsigned* __restrict__ gid32){
  __shared__ unsigned sc[4][NG];
  const int t    = threadIdx.x;
  const int lane = t & 63;
  const int w    = t >> 6;
  sc[0][t] = 0u; sc[1][t] = 0u; sc[2][t] = 0u; sc[3][t] = 0u;
  __syncthreads();

  const int b = blockIdx.x / NC;
  const int c = blockIdx.x % NC;
  const size_t base = (size_t)b*NN + (size_t)c*CH;
  const int4* v4 = (const int4*)(vr + base);

#pragma unroll
  for (int i = 0; i < 4; i++){
    int idx = w*256 + i*64 + lane;
    int4 v = v4[idx];
    atomicAdd(&sc[w][v.x], 1u);
    atomicAdd(&sc[w][v.y], 1u);
    atomicAdd(&sc[w][v.z], 1u);
    atomicAdd(&sc[w][v.w], 1u);
    gid32[(base >> 2) + idx] =
      (unsigned)v.x | ((unsigned)v.y << 8) | ((unsigned)v.z << 16) | ((unsigned)v.w << 24);
  }
  __syncthreads();

  unsigned c0 = sc[0][t], c1 = sc[1][t], c2 = sc[2][t], c3 = sc[3][t];
  const size_t cb = (size_t)b*NC + c;
  wcnt16[cb*NG + t] = (unsigned long long)c0
                    | ((unsigned long long)c1 << 16)
                    | ((unsigned long long)c2 << 32)
                    | ((unsigned long long)c3 << 48);
}

// ---- Pass 2: LDS-staged stable sort of each chunk + coalesced flush ----
// Offsets self-computed from the L2-hot wcnt16 column (R6-proven). Placement
// EXPERIMENT this round: per-element slot = ds_add_rtn (LDS atomicAdd return)
// on the seeded running counter, replacing the 8-ballot rank machinery.
// Per-wave DS ops execute in program order, so stripe order is preserved;
// within-instruction same-group collisions rely on lane-ordered atomic
// arbitration (verified by the harness's bit-exact check).
__global__ __launch_bounds__(256) void k_scatter(const float* __restrict__ pr,
                                                 const unsigned* __restrict__ gid32,
                                                 const unsigned long long* __restrict__ wcnt16,
                                                 float* __restrict__ sorted,
                                                 unsigned* __restrict__ grpbase,
                                                 unsigned* __restrict__ grplen){
  __shared__ float vbuf[CH];            // 16 KB sorted values
  __shared__ unsigned char gbuf[CH];    // 4 KB gid per sorted slot
  __shared__ unsigned wcnt[4][NG];      // running counters (seeded)
  __shared__ unsigned bias[NG];         // global_dest - local_base per group
  __shared__ unsigned wsumA[4];
  __shared__ unsigned wsumO[4];
  const int t    = threadIdx.x;
  const int lane = t & 63;
  const int w    = t >> 6;
  const int b = blockIdx.x / NC;
  const int c = blockIdx.x % NC;
  const size_t base = (size_t)b*NN + (size_t)c*CH;

  // phase 0: walk histogram column; fused shfl scans; seed running counters
  {
    const unsigned long long* tab = wcnt16 + (size_t)b*NC*NG + t;
    unsigned long long own = 0;
    unsigned tot_all = 0, tot_before = 0;
#pragma unroll 8
    for (int cc = 0; cc < NC; cc++){
      unsigned long long x = tab[(size_t)cc*NG];
      unsigned lo = (unsigned)x, hi = (unsigned)(x >> 32);
      unsigned tt = (lo & 0xFFFFu) + (lo >> 16) + (hi & 0xFFFFu) + (hi >> 16);
      tot_all += tt;
      if (cc < c)  tot_before += tt;   // uniform branch per block
      if (cc == c) own = x;            // uniform branch per block
    }
    unsigned lo = (unsigned)own, hi = (unsigned)(own >> 32);
    unsigned w0 = lo & 0xFFFFu, w1 = lo >> 16, w2 = hi & 0xFFFFu, w3 = hi >> 16;
    unsigned tot_own = w0 + w1 + w2 + w3;

    unsigned va = tot_all, vo = tot_own;        // wave-inclusive scans
#pragma unroll
    for (int d = 1; d < 64; d <<= 1){
      unsigned ya = __shfl_up(va, d, 64);
      unsigned yo = __shfl_up(vo, d, 64);
      if (lane >= d){ va += ya; vo += yo; }
    }
    if (lane == 63){ wsumA[w] = va; wsumO[w] = vo; }
    __syncthreads();
    unsigned preA = 0, preO = 0;
#pragma unroll
    for (int k = 0; k < 3; k++) if (k < w){ preA += wsumA[k]; preO += wsumO[k]; }
    unsigned base_g = preA + va - tot_all;      // group base (global)
    unsigned lb     = preO + vo - tot_own;      // local exclusive prefix
    wcnt[0][t] = lb;
    wcnt[1][t] = lb + w0;
    wcnt[2][t] = lb + w0 + w1;
    wcnt[3][t] = lb + w0 + w1 + w2;
    bias[t] = (base_g + tot_before) - lb;
    if (c == 0){                                // publish for k_sum
      grpbase[b*NG + t] = base_g;
      grplen [b*NG + t] = tot_all;
    }
  }
  __syncthreads();

  // phase 1: stable scatter into LDS via ds_add_rtn placement (per wave,
  // element order; stripes in program order, pipelined independent atomics)
  {
    const float*    psrc = pr    + base        + (size_t)w*SC;
    const unsigned* gsrc = gid32 + (base >> 2) + (size_t)w*(SC/4);
    const int shft = (lane & 3) * 8;

    float pv[16]; unsigned pk[16];              // batch all loads upfront
#pragma unroll
    for (int s = 0; s < 16; s++){
      pv[s] = psrc[s*64 + lane];
      pk[s] = gsrc[s*16 + (lane >> 2)];         // 4 lanes share one word
    }
#pragma unroll
    for (int s = 0; s < 16; s++){
      int g = (int)((pk[s] >> shft) & 255u);
      unsigned slot = atomicAdd(&wcnt[w][g], 1u);   // ds_add_rtn_u32
      vbuf[slot] = pv[s];
      gbuf[slot] = (unsigned char)g;
    }
  }
  __syncthreads();

  // phase 2: coalesced flush (consecutive p -> consecutive dest within runs)
  {
    float* dst = sorted + (size_t)b*NN;
    const unsigned* gbuf32 = (const unsigned*)gbuf;
#pragma unroll
    for (int k = 0; k < CH/256; k++){      // 16 iters
      int p = k*256 + t;
      unsigned packed = gbuf32[p >> 2];    // broadcast within 4 threads
      unsigned g = (packed >> ((p & 3) * 8)) & 255u;
      dst[bias[g] + (unsigned)p] = vbuf[p];
    }
  }
}

// ---- Pass 3: one LANE per (batch,group); float4 loads, 8-deep register
//      pipeline. Scalar head to 16B alignment + scalar tail keep the fp32 add
//      chain in exact element order (bit-exact). ----
__global__ __launch_bounds__(32) void k_sum(const float* __restrict__ sorted,
                                            const unsigned* __restrict__ grpbase,
                                            const unsigned* __restrict__ grplen,
                                            float* __restrict__ gsum,
                                            float* __restrict__ gmn,
                                            float* __restrict__ gmx){
  const int lane = threadIdx.x;                  // 0..31
  const int b = blockIdx.x >> 3;                 // 8 blocks per batch
  const int g = ((blockIdx.x & 7) << 5) + lane;  // one group per lane

  const unsigned base = grpbase[b*NG + g];
  const unsigned len  = grplen [b*NG + g];
  const float* sp = sorted + (size_t)b*NN + base;

  float s = 0.0f, mn = INFINITY, mx = -INFINITY;

  unsigned head = (4u - ((unsigned)(((size_t)sp) >> 2) & 3u)) & 3u;
  if (head > len) head = len;
  for (unsigned i = 0; i < head; i++){
    float v = sp[i];
    s = __fadd_rn(s, v); mn = fminf(mn, v); mx = fmaxf(mx, v);
  }
  const float4* f4 = (const float4*)(sp + head);
  const unsigned rem   = len - head;
  const unsigned nfull = rem >> 4;               // 16-elem batches (4 x float4)

  float4 b0[4], b1[4], b2[4], b3[4], b4[4], b5[4], b6[4], b7[4];
#define LOADV(D, K) { D[0]=f4[(K)*4+0]; D[1]=f4[(K)*4+1]; D[2]=f4[(K)*4+2]; D[3]=f4[(K)*4+3]; }
#define CONS1(V)    { s=__fadd_rn(s,(V)); mn=fminf(mn,(V)); mx=fmaxf(mx,(V)); }
#define CONSV(D)    { _Pragma("unroll") for (int j = 0; j < 4; j++){ float4 q = D[j]; \
                      CONS1(q.x) CONS1(q.y) CONS1(q.z) CONS1(q.w) } }

  if (nfull > 0) LOADV(b0, 0)
  if (nfull > 1) LOADV(b1, 1)
  if (nfull > 2) LOADV(b2, 2)
  if (nfull > 3) LOADV(b3, 3)
  if (nfull > 4) LOADV(b4, 4)
  if (nfull > 5) LOADV(b5, 5)
  if (nfull > 6) LOADV(b6, 6)
  if (nfull > 7) LOADV(b7, 7)
  unsigned k = 0;
  for (; k + 8 <= nfull; k += 8){
    CONSV(b0) if (k +  8 < nfull) LOADV(b0, k +  8)
    CONSV(b1) if (k +  9 < nfull) LOADV(b1, k +  9)
    CONSV(b2) if (k + 10 < nfull) LOADV(b2, k + 10)
    CONSV(b3) if (k + 11 < nfull) LOADV(b3, k + 11)
    CONSV(b4) if (k + 12 < nfull) LOADV(b4, k + 12)
    CONSV(b5) if (k + 13 < nfull) LOADV(b5, k + 13)
    CONSV(b6) if (k + 14 < nfull) LOADV(b6, k + 14)
    CONSV(b7) if (k + 15 < nfull) LOADV(b7, k + 15)
  }
  {
    unsigned r = nfull - k;        // 0..7 remaining full batches in b0..b6
    if (r > 0) CONSV(b0)
    if (r > 1) CONSV(b1)
    if (r > 2) CONSV(b2)
    if (r > 3) CONSV(b3)
    if (r > 4) CONSV(b4)
    if (r > 5) CONSV(b5)
    if (r > 6) CONSV(b6)
  }
  for (unsigned i = head + (nfull << 4); i < len; i++){
    float v = sp[i];
    s = __fadd_rn(s, v); mn = fminf(mn, v); mx = fmaxf(mx, v);
  }
#undef LOADV
#undef CONS1
#undef CONSV

  gsum[b*NG + g] = s;
  gmn [b*NG + g] = mn;
  gmx [b*NG + g] = mx;
}

// ---- Pass 4: per-batch group pipeline (blend, stable rank, f0/f1, no_scale) ----
__global__ __launch_bounds__(256) void k_pipeline(const float* __restrict__ gsum,
                                                  const float* __restrict__ gmn,
                                                  const float* __restrict__ gmx,
                                                  const float* __restrict__ inp_means,
                                                  const float* __restrict__ Wv,
                                                  float* __restrict__ params){
  const int b = blockIdx.x;
  const int g = threadIdx.x;
  __shared__ float vm[NG];
  __shared__ float vs[NG];

  const float s   = gsum[b*NG + g];
  const float mnf = gmn [b*NG + g];
  const float mxf = gmx [b*NG + g];
  const float W0 = Wv[0], W1 = Wv[1];
  float mean = __fdiv_rn(__fadd_rn(__fmul_rn(inp_means[b*NG + g], W0),
                                   __fmul_rn(s, W1)),
                         __fadd_rn(W0, W1));
  vm[g] = mean;
  __syncthreads();

  int r = 0;
  for (int j = 0; j < NG; j++){
    float x = vm[j];
    r += (x < mean) || (x == mean && j < g);
  }
  vs[r] = mean;
  __syncthreads();

  float c0 = (r == 0)    ? vs[0]                     : vs[r-1];
  float c1 = vs[r];
  float c2 = (r == NG-1) ? __fmul_rn(vs[NG-1], 2.0f) : vs[r+1];
  float f0 = __fdiv_rn(__fadd_rn(c0, c1), 1.999f);
  float f1 = __fdiv_rn(__fadd_rn(c1, c2), 2.001f);

  bool ns = (mnf == mxf);
  params[(b*4 + 0)*NG + g] = ns ? 0.0f : mnf;
  params[(b*4 + 1)*NG + g] = ns ? 1.0f : __fsub_rn(mxf, mnf);
  params[(b*4 + 2)*NG + g] = ns ? 1.0f : __fsub_rn(f1, f0);
  params[(b*4 + 3)*NG + g] = ns ? 0.0f : f0;
}

// ---- Pass 5: per-element apply, fp32 replicating reference op order ----
static __device__ __forceinline__ float apply_one(float p, unsigned g,
                                                  const float* __restrict__ sp0,
                                                  const float* __restrict__ sp1,
                                                  const float* __restrict__ sp2,
                                                  const float* __restrict__ sp3){
  float t1  = __fsub_rn(p, sp0[g]);
  float t3  = __fdiv_rn(t1, sp1[g]);
  float t5  = __fmul_rn(t3, sp2[g]);
  float tmp = __fadd_rn(t5, sp3[g]);
  bool bad = __builtin_isnan(tmp) || (tmp == 0.0f);
  float s = __fdiv_rn(p, bad ? 1.0f : tmp);
  bool bad2 = bad || __builtin_isnan(s) || __builtin_isinf(s);
  float sc = bad2 ? 0.0f : s;
  return __fmul_rn(p, sc);
}

__global__ __launch_bounds__(256) void k_apply(const float* __restrict__ pr,
                                               const unsigned* __restrict__ gid32,
                                               const float* __restrict__ params,
                                               float* __restrict__ out){
  __shared__ float sp0[NG], sp1[NG], sp2[NG], sp3[NG];
  const int t = threadIdx.x;
  const int b = blockIdx.x / CD;
  const int c = blockIdx.x % CD;

  sp0[t] = params[(b*4 + 0)*NG + t];
  sp1[t] = params[(b*4 + 1)*NG + t];
  sp2[t] = params[(b*4 + 2)*NG + t];
  sp3[t] = params[(b*4 + 3)*NG + t];
  __syncthreads();

  const size_t base = (size_t)b*NN + (size_t)c*ELD;
  const float4* p4 = (const float4*)(pr + base);
  float4* o4 = (float4*)(out + base);

#pragma unroll
  for (int i = 0; i < ELD/1024; i++){
    float4 p = p4[i*256 + t];
    unsigned pk = gid32[(base >> 2) + i*256 + t];
    float4 r;
    r.x = apply_one(p.x,  pk        & 255u, sp0, sp1, sp2, sp3);
    r.y = apply_one(p.y, (pk >>  8) & 255u, sp0, sp1, sp2, sp3);
    r.z = apply_one(p.z, (pk >> 16) & 255u, sp0, sp1, sp2, sp3);
    r.w = apply_one(p.w,  pk >> 24,         sp0, sp1, sp2, sp3);
    o4[i*256 + t] = r;
  }
}

extern "C" void kernel_launch(void* const* d_in, const int* in_sizes, int n_in,
                              void* d_out, int out_size, void* d_ws, size_t ws_size,
                              hipStream_t stream){
  const float* pr        = (const float*)d_in[0];
  const float* inp_means = (const float*)d_in[1];
  const int*   vr        = (const int*)d_in[2];
  const float* W         = (const float*)d_in[3];
  float* out = (float*)d_out;

  char* ws = (char*)d_ws;
  size_t o = 0;
  unsigned long long* wcnt16 = (unsigned long long*)(ws + o); o += (size_t)NB*NC*NG*8; // 4 MB
  unsigned* gid32   = (unsigned*)(ws + o); o += (size_t)NB*NN;       // 8 MB packed u8 gids
  unsigned* grpbase = (unsigned*)(ws + o); o += (size_t)NB*NG*4;     // 32 KB
  unsigned* grplen  = (unsigned*)(ws + o); o += (size_t)NB*NG*4;
  float*    gsum    = (float*)   (ws + o); o += (size_t)NB*NG*4;
  float*    gmn     = (float*)   (ws + o); o += (size_t)NB*NG*4;
  float*    gmx     = (float*)   (ws + o); o += (size_t)NB*NG*4;
  float*    params  = (float*)   (ws + o); o += (size_t)NB*NG*16;    // 128 KB (SoA)
  // sorted values live in d_out (fully overwritten by k_apply afterwards)
  float* sorted = out;

  k_count   <<<NB*NC, 256, 0, stream>>>(vr, wcnt16, gid32);
  k_scatter <<<NB*NC, 256, 0, stream>>>(pr, gid32, wcnt16, sorted, grpbase, grplen);
  k_sum     <<<NB*8,   32, 0, stream>>>(sorted, grpbase, grplen, gsum, gmn, gmx);
  k_pipeline<<<NB,    256, 0, stream>>>(gsum, gmn, gmx, inp_means, W, params);
  k_apply   <<<NB*CD, 256, 0, stream>>>(pr, gid32, params, out);
}